// Round 11
// baseline (207.740 us; speedup 1.0000x reference)
//
#include <hip/hip_runtime.h>
#include <math.h>

#define NB 4
#define NT 256
#define NS 1024
#define NH 256
#define SBK 64          // s window per item (1 s per lane)
#define NSQ (NS / SBK)  // 16
#define WT 4            // t rows per item
#define NTQ (NT / WT)   // 64 t-quads
#define NWORK (NB * NTQ * NSQ)  // 4096 items
#define BS (NB * NS)

typedef _Float16 half4 __attribute__((ext_vector_type(4)));

static constexpr float CTWO   = 2.8853900817779268f; // 2*log2(e)
static constexpr float LOG2E  = 1.4426950408889634f;
static constexpr float ACLAMP = 62.0f;

// ---------- merged projection (R9/R10 layout: tet contiguous per-(b,sq) window) ----------
__global__ __launch_bounds__(256) void proj_kernel(const float* __restrict__ Q,
                                                   const float* __restrict__ E,
                                                   const float* __restrict__ W_h,
                                                   const float* __restrict__ W_s,
                                                   float* __restrict__ tq,
                                                   float* __restrict__ tet) {
  __shared__ float As[32][68];
  __shared__ float Bs[32][68];
  const int tid = threadIdx.x;
  int r0 = blockIdx.x * 64;
  const int n0 = blockIdx.y * 64;
  const bool is_q = (r0 < NB * NT);
  const float* A;
  const float* W;
  if (is_q) { A = Q; W = W_h; }
  else      { A = E; W = W_s; r0 -= NB * NT; }
  const int tx = tid & 15;
  const int ty = tid >> 4;
  float acc[4][4] = {};
  for (int k0 = 0; k0 < NH; k0 += 32) {
    {
      const int r = tid >> 2;
      const int kq = (tid & 3) * 8;
      const float* src = A + (size_t)(r0 + r) * NH + k0 + kq;
      float4 v0 = *(const float4*)(src);
      float4 v1 = *(const float4*)(src + 4);
      As[kq + 0][r] = v0.x; As[kq + 1][r] = v0.y; As[kq + 2][r] = v0.z; As[kq + 3][r] = v0.w;
      As[kq + 4][r] = v1.x; As[kq + 5][r] = v1.y; As[kq + 6][r] = v1.z; As[kq + 7][r] = v1.w;
    }
    {
      const int k = tid >> 3;
      const int nq = (tid & 7) * 8;
      const float* src = W + (size_t)(k0 + k) * NH + n0 + nq;
      *(float4*)&Bs[k][nq]     = *(const float4*)(src);
      *(float4*)&Bs[k][nq + 4] = *(const float4*)(src + 4);
    }
    __syncthreads();
    #pragma unroll
    for (int k = 0; k < 32; ++k) {
      float4 a = *(const float4*)&As[k][ty * 4];
      float4 b = *(const float4*)&Bs[k][tx * 4];
      const float av[4] = {a.x, a.y, a.z, a.w};
      const float bv[4] = {b.x, b.y, b.z, b.w};
      #pragma unroll
      for (int i = 0; i < 4; ++i)
        #pragma unroll
        for (int j = 0; j < 4; ++j)
          acc[i][j] = fmaf(av[i], bv[j], acc[i][j]);
    }
    __syncthreads();
  }
  #pragma unroll
  for (int i = 0; i < 4; ++i) {
    float vals[4];
    #pragma unroll
    for (int j = 0; j < 4; ++j) {
      float x = acc[i][j] * CTWO;
      x = fminf(fmaxf(x, -ACLAMP), ACLAMP);
      vals[j] = __builtin_amdgcn_exp2f(x);
    }
    const int r = r0 + ty * 4 + i;
    if (is_q) {
      #pragma unroll
      for (int j = 0; j < 4; ++j)
        tq[(size_t)r * NH + n0 + tx * 4 + j] = vals[j];
    } else {
      const int h4 = (n0 >> 2) + tx;
      const int b  = r >> 10;
      const int s  = r & 1023;
      const int sq = s >> 6;
      const int sl = s & 63;
      float4 w = {vals[0], vals[1], vals[2], vals[3]};
      *(float4*)&tet[(((size_t)(b * 16 + sq) * 64 + h4) * 64 + sl) * 4] = w;
    }
  }
}

// paired-rcp: v1/ta + v2/tb = (v1*tb + v2*ta) / (ta*tb)
#define PAIR(qa, ea, va, qb, eb, vb, ACC)                                  \
  {                                                                        \
    float ta = fmaf((qa), (ea), 1.0f);                                     \
    float tb = fmaf((qb), (eb), 1.0f);                                     \
    float num = fmaf((va), tb, (vb) * ta);                                 \
    float den = ta * tb;                                                   \
    ACC = fmaf(num, __builtin_amdgcn_rcpf(den), ACC);                      \
  }

// ---------- main: PERSISTENT blocks; each WAVE steals items (b, t-quad, sq)
// from a global counter. Fixes the static CU/XCD imbalance that left the
// machine 80% idle in R4-R10 (masked blocks + no backfill = long tail).
// Body = R8/R9 proven wave body: contiguous tet stream, zero barriers. ----------
__global__ __launch_bounds__(256) void attn_main_kernel(
    const float4* __restrict__ tqq,   // [row][64] float4 view of tq
    const float4* __restrict__ tet,   // [(b,sq)][h4][64] float4 tiled te
    const float4* __restrict__ enc4,  // [row][64] float4 view of enc
    const int* __restrict__ src_len,
    const float4* __restrict__ vq,    // [64]
    half4* __restrict__ poh, float* __restrict__ mbuf, float* __restrict__ lbuf,
    int* __restrict__ ctr) {
  __shared__ float4 p_lds[4 * SBK];   // [wave][s] probs (4 KB)
  const int tid = threadIdx.x;
  const int wid = tid >> 6;
  const int lane = tid & 63;

  // sum(v): computed once, reused for every item
  float sumv;
  {
    float4 v4 = vq[lane];
    float sv = (v4.x + v4.y) + (v4.z + v4.w);
    #pragma unroll
    for (int o = 32; o > 0; o >>= 1) sv += __shfl_xor(sv, o, 64);
    sumv = sv;
  }

  for (;;) {
    int item = 0;
    if (lane == 0) item = atomicAdd(ctr, 1);
    item = __shfl(item, 0, 64);           // wave-uniform
    if (item >= NWORK) break;

    // item -> (b, sq, tquad); consecutive items share (b,sq) window (locality)
    const int b  = item >> 10;
    const int sq = (item >> 6) & 15;
    const int tquad = item & 63;
    const int len = src_len[b];
    const int s0 = sq * SBK;
    if (s0 >= len) continue;              // masked: combine recomputes validity

    const int wrow = b * NT + tquad * WT;
    const int gs0 = b * NS + s0;
    const bool ok = (s0 + lane) < len;

    // ---- score: 64 h4 iters over contiguous 64KB window ----
    float acc[WT] = {0.f, 0.f, 0.f, 0.f};
    const float4* tep = tet + (size_t)(b * 16 + sq) * 4096 + lane;
    const float4* qp  = tqq + (size_t)wrow * 64;
    #pragma unroll 8
    for (int h4 = 0; h4 < 64; ++h4) {
      const float4 e  = tep[h4 * 64];           // coalesced, sequential lines
      const float4 vv = vq[h4];                 // broadcast, L1-hot
      #pragma unroll
      for (int t = 0; t < WT; ++t) {
        const float4 q = qp[t * 64 + h4];       // broadcast, L1-hot
        PAIR(q.x, e.x, vv.x, q.y, e.y, vv.y, acc[t]);
        PAIR(q.z, e.z, vv.z, q.w, e.w, vv.w, acc[t]);
      }
    }

    // ---- wave-local softmax (lane owns 1 s) ----
    float pv[WT];
    #pragma unroll
    for (int t = 0; t < WT; ++t) {
      float x = ok ? fmaf(-2.f, acc[t], sumv) : -INFINITY;
      float m = x;
      #pragma unroll
      for (int o = 32; o > 0; o >>= 1) m = fmaxf(m, __shfl_xor(m, o, 64));
      float p = __builtin_amdgcn_exp2f((x - m) * LOG2E);  // -inf -> 0
      float l = p;
      #pragma unroll
      for (int o = 32; o > 0; o >>= 1) l += __shfl_xor(l, o, 64);
      pv[t] = p;
      if (lane == 0) {
        mbuf[(size_t)(wrow + t) * NSQ + sq] = m;
        lbuf[(size_t)(wrow + t) * NSQ + sq] = l;
      }
    }
    // transpose p to [s][t] via same-wave LDS (lgkmcnt only; no barrier)
    p_lds[wid * SBK + lane] = make_float4(pv[0], pv[1], pv[2], pv[3]);

    // ---- PV: 64 s iters, sequential enc stream ----
    float4 o[WT];
    #pragma unroll
    for (int t = 0; t < WT; ++t) o[t] = make_float4(0.f, 0.f, 0.f, 0.f);
    const float4* ep = enc4 + (size_t)gs0 * 64 + lane;
    #pragma unroll 4
    for (int s = 0; s < SBK; ++s) {
      const float4 e = ep[(size_t)s * 64];      // coalesced, sequential lines
      const float4 p = p_lds[wid * SBK + s];    // same-addr broadcast
      o[0].x = fmaf(p.x, e.x, o[0].x); o[0].y = fmaf(p.x, e.y, o[0].y);
      o[0].z = fmaf(p.x, e.z, o[0].z); o[0].w = fmaf(p.x, e.w, o[0].w);
      o[1].x = fmaf(p.y, e.x, o[1].x); o[1].y = fmaf(p.y, e.y, o[1].y);
      o[1].z = fmaf(p.y, e.z, o[1].z); o[1].w = fmaf(p.y, e.w, o[1].w);
      o[2].x = fmaf(p.z, e.x, o[2].x); o[2].y = fmaf(p.z, e.y, o[2].y);
      o[2].z = fmaf(p.z, e.z, o[2].z); o[2].w = fmaf(p.z, e.w, o[2].w);
      o[3].x = fmaf(p.w, e.x, o[3].x); o[3].y = fmaf(p.w, e.y, o[3].y);
      o[3].z = fmaf(p.w, e.z, o[3].z); o[3].w = fmaf(p.w, e.w, o[3].w);
    }
    #pragma unroll
    for (int t = 0; t < WT; ++t) {
      half4 h;
      h.x = (_Float16)o[t].x; h.y = (_Float16)o[t].y;
      h.z = (_Float16)o[t].z; h.w = (_Float16)o[t].w;
      poh[((size_t)(wrow + t) * NSQ + sq) * 64 + lane] = h;
    }
  }
}

// ---------- combine: validity recomputed from src_len (masked windows never
// written by attn) ----------
__global__ __launch_bounds__(256) void combine_kernel(const half4* __restrict__ poh,
                                                      const float* __restrict__ mbuf,
                                                      const float* __restrict__ lbuf,
                                                      const int* __restrict__ src_len,
                                                      float4* __restrict__ out4) {
  const int bt = blockIdx.x * 4 + (threadIdx.x >> 6);
  const int lane = threadIdx.x & 63;
  const int len = src_len[bt >> 8];       // bt / NT = batch
  const int nvalid = (len + SBK - 1) / SBK;
  float m[NSQ], l[NSQ];
  float M = -INFINITY;
  for (int i = 0; i < nvalid; ++i) {
    m[i] = mbuf[(size_t)bt * NSQ + i];
    l[i] = lbuf[(size_t)bt * NSQ + i];
    M = fmaxf(M, m[i]);
  }
  float L = 0.f;
  float4 o = make_float4(0.f, 0.f, 0.f, 0.f);
  for (int i = 0; i < nvalid; ++i) {
    float w = __builtin_amdgcn_exp2f((m[i] - M) * LOG2E);
    L = fmaf(w, l[i], L);
    half4 h = poh[((size_t)bt * NSQ + i) * 64 + lane];
    o.x = fmaf(w, (float)h.x, o.x);
    o.y = fmaf(w, (float)h.y, o.y);
    o.z = fmaf(w, (float)h.z, o.z);
    o.w = fmaf(w, (float)h.w, o.w);
  }
  const float r = __builtin_amdgcn_rcpf(L);
  o.x *= r; o.y *= r; o.z *= r; o.w *= r;
  out4[(size_t)bt * 64 + lane] = o;
}

extern "C" void kernel_launch(void* const* d_in, const int* in_sizes, int n_in,
                              void* d_out, int out_size, void* d_ws, size_t ws_size,
                              hipStream_t stream) {
  const float* query = (const float*)d_in[0];
  const float* enc   = (const float*)d_in[1];
  const int*   slen  = (const int*)d_in[2];
  const float* W_h   = (const float*)d_in[3];
  const float* W_s   = (const float*)d_in[4];
  const float* v     = (const float*)d_in[5];
  float* out = (float*)d_out;

  float* ws = (float*)d_ws;
  float* tq  = ws;                                 // NB*NT*NH floats   (1 MB)
  float* tet = tq + (size_t)NB * NT * NH;          // NB*NS*NH floats   (4 MB)
  half4* poh = (half4*)(tet + (size_t)NB * NS * NH);      // NB*NT*NSQ*NH halves
  float* mb  = (float*)((char*)poh + (size_t)NB * NT * NSQ * NH * 2);
  float* lb  = mb + (size_t)NB * NT * NSQ;
  int*   ctr = (int*)(lb + (size_t)NB * NT * NSQ);

  hipMemsetAsync(ctr, 0, sizeof(int), stream);
  hipLaunchKernelGGL(proj_kernel, dim3((NB * (NT + NS)) / 64, NH / 64), dim3(256), 0, stream,
                     query, enc, W_h, W_s, tq, tet);
  // persistent: 2048 blocks (full residency), waves steal 4096 items
  hipLaunchKernelGGL(attn_main_kernel, dim3(2048), dim3(256), 0, stream,
                     (const float4*)tq, (const float4*)tet, (const float4*)enc, slen,
                     (const float4*)v, poh, mb, lb, ctr);
  hipLaunchKernelGGL(combine_kernel, dim3(NB * NT / 4), dim3(256), 0, stream,
                     poh, mb, lb, slen, (float4*)out);
}

// Round 12
// 76.494 us; speedup vs baseline: 2.7158x; 2.7158x over previous
//
#include <hip/hip_runtime.h>
#include <math.h>

#define NB 4
#define NT 256
#define NS 1024
#define NH 256
#define SBK 64          // s window (1 s per lane)
#define NSQ (NS / SBK)  // 16
#define WT 4            // t rows per wave
#define BS (NB * NS)

typedef _Float16 half4 __attribute__((ext_vector_type(4)));

static constexpr float CTWO   = 2.8853900817779268f; // 2*log2(e)
static constexpr float LOG2E  = 1.4426950408889634f;
static constexpr float ACLAMP = 62.0f;

// ---------- merged projection (tet contiguous per-(b,sq) window; proven) ----------
__global__ __launch_bounds__(256) void proj_kernel(const float* __restrict__ Q,
                                                   const float* __restrict__ E,
                                                   const float* __restrict__ W_h,
                                                   const float* __restrict__ W_s,
                                                   float* __restrict__ tq,
                                                   float* __restrict__ tet) {
  __shared__ float As[32][68];
  __shared__ float Bs[32][68];
  const int tid = threadIdx.x;
  int r0 = blockIdx.x * 64;
  const int n0 = blockIdx.y * 64;
  const bool is_q = (r0 < NB * NT);
  const float* A;
  const float* W;
  if (is_q) { A = Q; W = W_h; }
  else      { A = E; W = W_s; r0 -= NB * NT; }
  const int tx = tid & 15;
  const int ty = tid >> 4;
  float acc[4][4] = {};
  for (int k0 = 0; k0 < NH; k0 += 32) {
    {
      const int r = tid >> 2;
      const int kq = (tid & 3) * 8;
      const float* src = A + (size_t)(r0 + r) * NH + k0 + kq;
      float4 v0 = *(const float4*)(src);
      float4 v1 = *(const float4*)(src + 4);
      As[kq + 0][r] = v0.x; As[kq + 1][r] = v0.y; As[kq + 2][r] = v0.z; As[kq + 3][r] = v0.w;
      As[kq + 4][r] = v1.x; As[kq + 5][r] = v1.y; As[kq + 6][r] = v1.z; As[kq + 7][r] = v1.w;
    }
    {
      const int k = tid >> 3;
      const int nq = (tid & 7) * 8;
      const float* src = W + (size_t)(k0 + k) * NH + n0 + nq;
      *(float4*)&Bs[k][nq]     = *(const float4*)(src);
      *(float4*)&Bs[k][nq + 4] = *(const float4*)(src + 4);
    }
    __syncthreads();
    #pragma unroll
    for (int k = 0; k < 32; ++k) {
      float4 a = *(const float4*)&As[k][ty * 4];
      float4 b = *(const float4*)&Bs[k][tx * 4];
      const float av[4] = {a.x, a.y, a.z, a.w};
      const float bv[4] = {b.x, b.y, b.z, b.w};
      #pragma unroll
      for (int i = 0; i < 4; ++i)
        #pragma unroll
        for (int j = 0; j < 4; ++j)
          acc[i][j] = fmaf(av[i], bv[j], acc[i][j]);
    }
    __syncthreads();
  }
  #pragma unroll
  for (int i = 0; i < 4; ++i) {
    float vals[4];
    #pragma unroll
    for (int j = 0; j < 4; ++j) {
      float x = acc[i][j] * CTWO;
      x = fminf(fmaxf(x, -ACLAMP), ACLAMP);
      vals[j] = __builtin_amdgcn_exp2f(x);
    }
    const int r = r0 + ty * 4 + i;
    if (is_q) {
      #pragma unroll
      for (int j = 0; j < 4; ++j)
        tq[(size_t)r * NH + n0 + tx * 4 + j] = vals[j];
    } else {
      const int h4 = (n0 >> 2) + tx;
      const int b  = r >> 10;
      const int s  = r & 1023;
      const int sq = s >> 6;
      const int sl = s & 63;
      float4 w = {vals[0], vals[1], vals[2], vals[3]};
      *(float4*)&tet[(((size_t)(b * 16 + sq) * 64 + h4) * 64 + sl) * 4] = w;
    }
  }
}

// paired-rcp: v1/ta + v2/tb = (v1*tb + v2*ta) / (ta*tb)
#define PAIR(qa, ea, va, qb, eb, vb, ACC)                                  \
  {                                                                        \
    float ta = fmaf((qa), (ea), 1.0f);                                     \
    float tb = fmaf((qb), (eb), 1.0f);                                     \
    float num = fmaf((va), tb, (vb) * ta);                                 \
    float den = ta * tb;                                                   \
    ACC = fmaf(num, __builtin_amdgcn_rcpf(den), ACC);                      \
  }

// ---------- main: block = 2 waves, wave = (b, 4 t-rows, 64-s window).
// (1) bit-reversed bx->(b,sq,to) decode: masked/valid blocks uniformly mixed
//     on every CU (R8 pinned each CU to one (b,sq) -> half the machine idle).
// (2) q and v staged in LDS (lgkm broadcast reads); te is the ONLY vmcnt
//     stream in the score loop (64 sequential dwordx4, 8 in flight). ----------
__global__ __launch_bounds__(128) void attn_main_kernel(
    const float4* __restrict__ tqq,   // [row][64] float4 view of tq
    const float4* __restrict__ tet,   // [(b,sq)][h4][64] float4 tiled te
    const float4* __restrict__ enc4,  // [row][64] float4 view of enc
    const int* __restrict__ src_len,
    const float4* __restrict__ vq,    // [64]
    half4* __restrict__ poh, float* __restrict__ mbuf, float* __restrict__ lbuf) {
  __shared__ float4 v_lds[64];        // 1 KB
  __shared__ float4 q_lds[2 * 256];   // 8 KB: [wave][t][h4]
  __shared__ float4 p_lds[2 * 64];    // 2 KB: [wave][s]
  const int tid = threadIdx.x;
  const int w = tid >> 6;
  const int lane = tid & 63;
  const unsigned rev = __brev((unsigned)blockIdx.x) >> 21;  // 11-bit reversal
  const int b  = rev & 3;
  const int sq = (((rev >> 2) & 15) + 4 * b) & 15;
  const int to = rev >> 6;             // [0,32) t-oct (8 rows per block)
  const int len = src_len[b];
  const int s0 = sq * SBK;
  if (s0 >= len) return;               // masked; combine recomputes validity

  if (tid < 64) v_lds[tid] = vq[tid];
  __syncthreads();

  // sum(v)
  float sumv;
  {
    float4 v4 = v_lds[lane];
    float sv = (v4.x + v4.y) + (v4.z + v4.w);
    #pragma unroll
    for (int o = 32; o > 0; o >>= 1) sv += __shfl_xor(sv, o, 64);
    sumv = sv;
  }

  const int wrow = b * NT + to * 8 + w * WT;
  const int gs0 = b * NS + s0;
  const bool ok = (s0 + lane) < len;

  // stage this wave's 4 q rows (coalesced; same-wave write->read, no barrier)
  {
    const float4* qg = tqq + (size_t)wrow * 64;
    #pragma unroll
    for (int i = 0; i < 4; ++i)
      q_lds[w * 256 + i * 64 + lane] = qg[i * 64 + lane];
  }

  // ---- score: te = sole VMEM stream (contiguous 64KB window) ----
  float acc[WT] = {0.f, 0.f, 0.f, 0.f};
  const float4* tep = tet + (size_t)(b * 16 + sq) * 4096 + lane;
  #pragma unroll 8
  for (int h4 = 0; h4 < 64; ++h4) {
    const float4 e  = tep[h4 * 64];           // sequential 1KB lines
    const float4 vv = v_lds[h4];              // ds broadcast
    #pragma unroll
    for (int t = 0; t < WT; ++t) {
      const float4 q = q_lds[w * 256 + t * 64 + h4];  // ds broadcast
      PAIR(q.x, e.x, vv.x, q.y, e.y, vv.y, acc[t]);
      PAIR(q.z, e.z, vv.z, q.w, e.w, vv.w, acc[t]);
    }
  }

  // ---- wave-local softmax (lane owns 1 s) ----
  float pv[WT];
  #pragma unroll
  for (int t = 0; t < WT; ++t) {
    float x = ok ? fmaf(-2.f, acc[t], sumv) : -INFINITY;
    float m = x;
    #pragma unroll
    for (int o = 32; o > 0; o >>= 1) m = fmaxf(m, __shfl_xor(m, o, 64));
    float p = __builtin_amdgcn_exp2f((x - m) * LOG2E);  // -inf -> 0
    float l = p;
    #pragma unroll
    for (int o = 32; o > 0; o >>= 1) l += __shfl_xor(l, o, 64);
    pv[t] = p;
    if (lane == 0) {
      mbuf[(size_t)(wrow + t) * NSQ + sq] = m;
      lbuf[(size_t)(wrow + t) * NSQ + sq] = l;
    }
  }
  // transpose p to [s][t] via same-wave LDS (lgkm only; no barrier)
  p_lds[w * 64 + lane] = make_float4(pv[0], pv[1], pv[2], pv[3]);

  // ---- PV: enc = sole VMEM stream (contiguous 64KB) ----
  float4 o[WT];
  #pragma unroll
  for (int t = 0; t < WT; ++t) o[t] = make_float4(0.f, 0.f, 0.f, 0.f);
  const float4* ep = enc4 + (size_t)gs0 * 64 + lane;
  #pragma unroll 4
  for (int s = 0; s < SBK; ++s) {
    const float4 e = ep[(size_t)s * 64];
    const float4 p = p_lds[w * 64 + s];       // ds broadcast
    o[0].x = fmaf(p.x, e.x, o[0].x); o[0].y = fmaf(p.x, e.y, o[0].y);
    o[0].z = fmaf(p.x, e.z, o[0].z); o[0].w = fmaf(p.x, e.w, o[0].w);
    o[1].x = fmaf(p.y, e.x, o[1].x); o[1].y = fmaf(p.y, e.y, o[1].y);
    o[1].z = fmaf(p.y, e.z, o[1].z); o[1].w = fmaf(p.y, e.w, o[1].w);
    o[2].x = fmaf(p.z, e.x, o[2].x); o[2].y = fmaf(p.z, e.y, o[2].y);
    o[2].z = fmaf(p.z, e.z, o[2].z); o[2].w = fmaf(p.z, e.w, o[2].w);
    o[3].x = fmaf(p.w, e.x, o[3].x); o[3].y = fmaf(p.w, e.y, o[3].y);
    o[3].z = fmaf(p.w, e.z, o[3].z); o[3].w = fmaf(p.w, e.w, o[3].w);
  }
  #pragma unroll
  for (int t = 0; t < WT; ++t) {
    half4 h;
    h.x = (_Float16)o[t].x; h.y = (_Float16)o[t].y;
    h.z = (_Float16)o[t].z; h.w = (_Float16)o[t].w;
    poh[((size_t)(wrow + t) * NSQ + sq) * 64 + lane] = h;
  }
}

// ---------- combine: validity recomputed from src_len ----------
__global__ __launch_bounds__(256) void combine_kernel(const half4* __restrict__ poh,
                                                      const float* __restrict__ mbuf,
                                                      const float* __restrict__ lbuf,
                                                      const int* __restrict__ src_len,
                                                      float4* __restrict__ out4) {
  const int bt = blockIdx.x * 4 + (threadIdx.x >> 6);
  const int lane = threadIdx.x & 63;
  const int len = src_len[bt >> 8];
  const int nvalid = (len + SBK - 1) / SBK;
  float m[NSQ], l[NSQ];
  float M = -INFINITY;
  for (int i = 0; i < nvalid; ++i) {
    m[i] = mbuf[(size_t)bt * NSQ + i];
    l[i] = lbuf[(size_t)bt * NSQ + i];
    M = fmaxf(M, m[i]);
  }
  float L = 0.f;
  float4 o = make_float4(0.f, 0.f, 0.f, 0.f);
  for (int i = 0; i < nvalid; ++i) {
    float w = __builtin_amdgcn_exp2f((m[i] - M) * LOG2E);
    L = fmaf(w, l[i], L);
    half4 h = poh[((size_t)bt * NSQ + i) * 64 + lane];
    o.x = fmaf(w, (float)h.x, o.x);
    o.y = fmaf(w, (float)h.y, o.y);
    o.z = fmaf(w, (float)h.z, o.z);
    o.w = fmaf(w, (float)h.w, o.w);
  }
  const float r = __builtin_amdgcn_rcpf(L);
  o.x *= r; o.y *= r; o.z *= r; o.w *= r;
  out4[(size_t)bt * 64 + lane] = o;
}

extern "C" void kernel_launch(void* const* d_in, const int* in_sizes, int n_in,
                              void* d_out, int out_size, void* d_ws, size_t ws_size,
                              hipStream_t stream) {
  const float* query = (const float*)d_in[0];
  const float* enc   = (const float*)d_in[1];
  const int*   slen  = (const int*)d_in[2];
  const float* W_h   = (const float*)d_in[3];
  const float* W_s   = (const float*)d_in[4];
  const float* v     = (const float*)d_in[5];
  float* out = (float*)d_out;

  float* ws = (float*)d_ws;
  float* tq  = ws;                                 // NB*NT*NH floats
  float* tet = tq + (size_t)NB * NT * NH;          // NB*NS*NH floats (tiled)
  half4* poh = (half4*)(tet + (size_t)NB * NS * NH);
  float* mb  = (float*)((char*)poh + (size_t)NB * NT * NSQ * NH * 2);
  float* lb  = mb + (size_t)NB * NT * NSQ;

  hipLaunchKernelGGL(proj_kernel, dim3((NB * (NT + NS)) / 64, NH / 64), dim3(256), 0, stream,
                     query, enc, W_h, W_s, tq, tet);
  // 2048 blocks x 2 waves = 4096 waves, validity bit-reverse-interleaved
  hipLaunchKernelGGL(attn_main_kernel, dim3(2048), dim3(128), 0, stream,
                     (const float4*)tq, (const float4*)tet, (const float4*)enc, slen,
                     (const float4*)v, poh, mb, lb);
  hipLaunchKernelGGL(combine_kernel, dim3(NB * NT / 4), dim3(256), 0, stream,
                     poh, mb, lb, slen, (float4*)out);
}